// Round 16
// baseline (312.204 us; speedup 1.0000x reference)
//
#include <hip/hip_runtime.h>
#include <hip/hip_bf16.h>
#include <stdint.h>

// Problem geometry (fixed by reference)
#define NQ 4096      // 64*8*8 query rows
#define NS 40960     // 32768 (s1) + 8192 (s_src)
#define CDIM 512
#define QT 128       // q rows per block: 4 waves x 32 q
#define SC 32        // s rows per chunk (register-blocking unit only — no LDS)
#define NSPLIT 32    // s-dimension splits
#define SPER (NS / NSPLIT)   // 1280
#define NCHUNK (SPER / SC)   // 40
#define NCAND 960    // per-row candidates: 32 splits * 2 lane-halves * 15

typedef float f32x16 __attribute__((ext_vector_type(16)));
typedef unsigned int u32x4 __attribute__((ext_vector_type(4)));
typedef int i32x4 __attribute__((ext_vector_type(4)));
typedef int i32x8 __attribute__((ext_vector_type(8)));

__device__ __forceinline__ unsigned short f2bf(float f) {
    uint32_t u = __builtin_bit_cast(uint32_t, f);
    u += 0x7fffu + ((u >> 16) & 1u);   // RNE (finite values only here)
    return (unsigned short)(u >> 16);
}
__device__ __forceinline__ float bf2f(unsigned short u) {
    uint32_t x = ((uint32_t)u) << 16;
    return __builtin_bit_cast(float, x);
}

// fp4 e2m1 encode of y (already pre-scaled by 16; e8m0 operand scale 2^-4 undoes it).
__device__ __forceinline__ unsigned fp4enc(float y) {
    float m = fabsf(y);
    unsigned c = (m < 0.25f) ? 0u : (m < 0.75f) ? 1u : (m < 1.25f) ? 2u
               : (m < 1.75f) ? 3u : (m < 2.5f)  ? 4u : (m < 3.5f)  ? 5u
               : (m < 5.0f)  ? 6u : 7u;
    return c | ((__builtin_bit_cast(unsigned, y) >> 28) & 8u);
}

// Branchless sorted-desc insert: r[i] = med3(v, r[i-1], r[i]) for i=14..1, then max.
__device__ __forceinline__ void ins15(float (&r)[15], float v) {
#pragma unroll
    for (int i = 14; i >= 1; --i) r[i] = __builtin_amdgcn_fmed3f(v, r[i - 1], r[i]);
    r[0] = fmaxf(r[0], v);
}

// ---------------- Phase A1: pool q (4x4 mean) + row-normalize -> fp4 ----------------
__global__ __launch_bounds__(256) void pool_q_norm(const float* __restrict__ q,
                                                   unsigned char* __restrict__ qn) {
    int bb = blockIdx.x >> 3, h = blockIdx.x & 7;
    int t = threadIdx.x, lane = t & 63, wid = t >> 6;
    float vals[2][8];
    float ss[8] = {0, 0, 0, 0, 0, 0, 0, 0};
#pragma unroll
    for (int e = 0; e < 2; ++e) {
        int c = 2 * t + e;
        const float* base = q + ((size_t)(bb * 512 + c) * 1024 + 4 * h * 32);
#pragma unroll
        for (int w2 = 0; w2 < 8; ++w2) vals[e][w2] = 0.f;
#pragma unroll
        for (int i = 0; i < 4; ++i) {
            const float4* row = (const float4*)(base + i * 32);
#pragma unroll
            for (int w2 = 0; w2 < 8; ++w2) {
                float4 v = row[w2];
                vals[e][w2] += (v.x + v.y) + (v.z + v.w);
            }
        }
#pragma unroll
        for (int w2 = 0; w2 < 8; ++w2) {
            vals[e][w2] *= (1.f / 16.f);
            ss[w2] += vals[e][w2] * vals[e][w2];
        }
    }
    __shared__ float red[8][4];
#pragma unroll
    for (int k = 0; k < 8; ++k) {
        float v = ss[k];
#pragma unroll
        for (int o = 32; o > 0; o >>= 1) v += __shfl_xor(v, o, 64);
        if (lane == 0) red[k][wid] = v;
    }
    __syncthreads();
#pragma unroll
    for (int w2 = 0; w2 < 8; ++w2) {
        float inv16 = rsqrtf(red[w2][0] + red[w2][1] + red[w2][2] + red[w2][3]) * 16.f;
        unsigned e0 = fp4enc(vals[0][w2] * inv16);
        unsigned e1 = fp4enc(vals[1][w2] * inv16);
        qn[(size_t)(bb * 64 + h * 8 + w2) * 256 + t] = (unsigned char)(e0 | (e1 << 4));
    }
}

// ------- Phase A2: pool S at BOTH scales + row-normalize -> fp4 -------
__global__ __launch_bounds__(256) void pool_s_norm(const float* __restrict__ S,
                                                   unsigned char* __restrict__ sn) {
    int bb = blockIdx.x >> 3, h2 = blockIdx.x & 7;
    int t = threadIdx.x, lane = t & 63, wid = t >> 6;
    __shared__ unsigned short tile[40 * 512];   // 40KB raw-bf16 values
    __shared__ float rowsum[40];
#pragma unroll
    for (int e = 0; e < 2; ++e) {
        int c = 2 * t + e;
        const float* base = S + ((size_t)(bb * 512 + c) * 1024 + 4 * h2 * 32);
        float s1v[2][16];
#pragma unroll
        for (int j = 0; j < 2; ++j) {
            const float4* r0 = (const float4*)(base + (2 * j) * 32);
            const float4* r1 = (const float4*)(base + (2 * j + 1) * 32);
#pragma unroll
            for (int f = 0; f < 8; ++f) {
                float4 a = r0[f], b2 = r1[f];
                s1v[j][2 * f]     = (a.x + a.y + b2.x + b2.y) * 0.25f;
                s1v[j][2 * f + 1] = (a.z + a.w + b2.z + b2.w) * 0.25f;
            }
        }
#pragma unroll
        for (int j = 0; j < 2; ++j)
#pragma unroll
            for (int w1 = 0; w1 < 16; ++w1)
                tile[(j * 16 + w1) * 512 + c] = f2bf(s1v[j][w1]);
#pragma unroll
        for (int w2 = 0; w2 < 8; ++w2) {
            float src = (s1v[0][2 * w2] + s1v[0][2 * w2 + 1] +
                         s1v[1][2 * w2] + s1v[1][2 * w2 + 1]) * 0.25f;
            tile[(32 + w2) * 512 + c] = f2bf(src);
        }
    }
    __syncthreads();
    // Row sums-of-squares: wave wid owns rows 4k+wid; 64 lanes x 8 bf16 per row.
#pragma unroll
    for (int k = 0; k < 10; ++k) {
        int row = 4 * k + wid;
        u32x4 d = *(const u32x4*)(&tile[row * 512 + lane * 8]);
        float s = 0.f;
#pragma unroll
        for (int j = 0; j < 4; ++j) {
            float x0 = bf2f((unsigned short)(d[j] & 0xffffu));
            float x1 = bf2f((unsigned short)(d[j] >> 16));
            s += x0 * x0 + x1 * x1;
        }
#pragma unroll
        for (int o = 32; o > 0; o >>= 1) s += __shfl_xor(s, o, 64);
        if (lane == 0) rowsum[row] = s;
    }
    __syncthreads();
    // Scale + fp4 cast + coalesced 4B stores: 40 rows x 64 4B-units.
#pragma unroll
    for (int k = 0; k < 10; ++k) {
        int idx = t + 256 * k;
        int r = idx >> 6, seg = idx & 63;      // seg of 8 channels -> 4 bytes
        float inv16 = rsqrtf(rowsum[r]) * 16.f;
        const unsigned short* src = &tile[r * 512 + seg * 8];
        unsigned out = 0;
#pragma unroll
        for (int m = 0; m < 8; ++m)
            out |= fp4enc(bf2f(src[m]) * inv16) << (4 * m);
        int grow = (r < 32) ? (bb * 256 + (2 * h2 + (r >> 4)) * 16 + (r & 15))
                            : (32768 + bb * 64 + h2 * 8 + (r - 32));
        *(unsigned*)(sn + (size_t)grow * 256 + seg * 4) = out;
    }
}

// ---------------- Phase B: MX-fp4 32x32x64 MFMA, BARRIER-FREE, direct-global A ----------------
// R15 post-mortem: sim ~141us vs ~40us work floor — the gap was vmcnt waits + 40
// barriers with only 2 barrier-groups/CU. This version deletes ALL synchronization:
// no LDS, no global_load_lds, no barriers, no vmcnt asm. Each wave reads its 16B
// A-fragments directly from global (L1-resident: the 8KB fp4 chunk x few blocks fits
// 32KB L1; split 320KB fits XCD L2; XCD-pinned as before). Latency hides via
// occupancy: 32q/wave keeps live regs ~115 -> launch_bounds(256,4) = 128-VGPR cap
// = 16 waves/CU (4/SIMD, 2x R15) and the compiler freely hoists the 8 independent
// loads per chunk (counted vmcnt) — exactly what the barrier structure prevented.
// Scan-in-MFMA-shadow ping-pong (cA/pB static names) retained from R13.
// 1024 blocks x 256 threads: xcd=id&7, j=id>>3, y=xcd*4+(j&3), x=j>>2 (0..31).
__global__ __launch_bounds__(256, 4) void sim_topk(const unsigned char* __restrict__ qn,
                                                   const unsigned char* __restrict__ sn,
                                                   float* __restrict__ partial) {
    int id = blockIdx.x;
    int xcd = id & 7, j = id >> 3;     // j = 0..127
    int y = xcd * 4 + (j & 3);         // s-split 0..31, pinned to XCD
    int x = j >> 2;                    // q-tile 0..31
    int tid = threadIdx.x, lane = tid & 63, wid = tid >> 6;
    int rlo = lane & 31, hi = lane >> 5;
    int qbase = x * QT + wid * 32;
    int sbase = y * SPER;

    // B fragments (q side, fp4): 32 q rows. Lane's kstep-kk frag = 16B covering
    // channels [kk*64 + hi*32, +32).
    u32x4 b[8];
    {
        const unsigned char* qp = qn + (size_t)(qbase + rlo) * 256 + hi * 16;
#pragma unroll
        for (int kk = 0; kk < 8; ++kk) b[kk] = *(const u32x4*)(qp + kk * 32);
    }

    float r0[15];
#pragma unroll
    for (int i = 0; i < 15; ++i) r0[i] = -2.0f;   // below min cosine

    // One K=64 kstep: direct-global 16B A-read (row rlo of the chunk) -> scaled MFMA.
    auto kstep = [&](const unsigned char* s0, int kk, f32x16& acc) {
        u32x4 a4 = *(const u32x4*)(s0 + kk * 32);
        i32x8 a = __builtin_shufflevector(__builtin_bit_cast(i32x4, a4),
                                          (i32x4){0, 0, 0, 0}, 0, 1, 2, 3, 4, 5, 6, 7);
        i32x8 bk = __builtin_shufflevector(__builtin_bit_cast(i32x4, b[kk]),
                                           (i32x4){0, 0, 0, 0}, 0, 1, 2, 3, 4, 5, 6, 7);
        acc = __builtin_amdgcn_mfma_scale_f32_32x32x64_f8f6f4(
            a, bk, acc, 4, 4, 0, 0x7B7B7B7B, 0, 0x7B7B7B7B);
    };

    f32x16 cA, pB;                     // current / previous chunk accs (ping-pong)
#pragma unroll
    for (int e = 0; e < 16; ++e) pB[e] = -2.0f;

    // Lane's A-row base for chunk 0: row (sbase + rlo), byte offset hi*16 within slot.
    const unsigned char* sp = sn + (size_t)(sbase + rlo) * 256 + hi * 16;

    for (int it = 0; it < NCHUNK / 2; ++it) {
        // ---- even chunk 2it -> cA; scan pB (chunk 2it-1) in the MFMA shadow ----
#pragma unroll
        for (int kk = 0; kk < 8; ++kk) asm volatile("" : "+v"(b[kk]));
        const unsigned char* s0 = sp + (size_t)(2 * it) * SC * 256;
#pragma unroll
        for (int e = 0; e < 16; ++e) cA[e] = 0.f;
#pragma unroll
        for (int kk = 0; kk < 8; ++kk) {
            kstep(s0, kk, cA);
            ins15(r0, pB[2 * kk]);
            ins15(r0, pB[2 * kk + 1]);
        }
        // ---- odd chunk 2it+1 -> pB; scan cA (chunk 2it) ----
        const unsigned char* s1 = s0 + SC * 256;
#pragma unroll
        for (int e = 0; e < 16; ++e) pB[e] = 0.f;
#pragma unroll
        for (int kk = 0; kk < 8; ++kk) {
            kstep(s1, kk, pB);
            ins15(r0, cA[2 * kk]);
            ins15(r0, cA[2 * kk + 1]);
        }
    }
    // epilogue: scan the final chunk (NCHUNK-1)
#pragma unroll
    for (int e = 0; e < 16; ++e) ins15(r0, pB[e]);

    // Emit: partial[qrow][split][sub][15], sub = hi
    int q0 = qbase + rlo;
    float* dst = partial + (((size_t)q0 * NSPLIT + y) * 2 + hi) * 15;
#pragma unroll
    for (int i = 0; i < 15; ++i) dst[i] = r0[i];
}

// ---------------- Final: merge 960 candidates/row -> top15 -> LSE/top4 loss ----------------
// Wave per row, 4 rows/block, no per-round barriers, one atomicAdd per block.
__global__ __launch_bounds__(256) void topk_loss(const float* __restrict__ partial,
                                                 float* __restrict__ accum) {
    int t = threadIdx.x, lane = t & 63, wid = t >> 6;
    int r = blockIdx.x * 4 + wid;
    const float* src = partial + (size_t)r * NCAND;
    float v[15];
#pragma unroll
    for (int i = 0; i < 15; ++i) v[i] = src[lane + 64 * i];
    float m0 = 0.f, sexp = 0.f, top4 = 0.f;
#pragma unroll
    for (int round = 0; round < 15; ++round) {
        float m = v[0];
        int mi = lane * 16;
#pragma unroll
        for (int i = 1; i < 15; ++i)
            if (v[i] > m) { m = v[i]; mi = lane * 16 + i; }
#pragma unroll
        for (int o = 32; o > 0; o >>= 1) {
            float om = __shfl_xor(m, o, 64);
            int oi = __shfl_xor(mi, o, 64);
            if (om > m || (om == m && oi < mi)) { m = om; mi = oi; }
        }
        int wl = mi >> 4, wi = mi & 15;
#pragma unroll
        for (int i = 0; i < 15; ++i)
            if (i == wi && wl == lane) v[i] = -1e30f;   // static-index clear
        if (round == 0) m0 = m;
        sexp += expf(m - m0);
        if (round < 4) top4 += m;
    }
    float loss = m0 + logf(sexp) - 0.25f * top4;
    __shared__ float red[4];
    if (lane == 0) red[wid] = loss;
    __syncthreads();
    if (t == 0) atomicAdd(accum, red[0] + red[1] + red[2] + red[3]);
}

__global__ void finalize_out(const float* __restrict__ accum, float* __restrict__ out) {
    out[0] = accum[0] * (1.0f / (float)NQ);
}

// ---------------- Launch ----------------
extern "C" void kernel_launch(void* const* d_in, const int* in_sizes, int n_in,
                              void* d_out, int out_size, void* d_ws, size_t ws_size,
                              hipStream_t stream) {
    (void)in_sizes; (void)n_in; (void)out_size; (void)ws_size;
    const float* q = (const float*)d_in[0];
    const float* S = (const float*)d_in[1];
    char* ws = (char*)d_ws;
    unsigned char* qn = (unsigned char*)ws;                          //  1,048,576 B
    unsigned char* sn = (unsigned char*)(ws + 1048576);              // 10,485,760 B
    float* partial = (float*)(ws + 1048576 + 10485760);              // 15,728,640 B
    float* accum   = (float*)(ws + 1048576 + 10485760 + 15728640);   // 4 B

    hipMemsetAsync(accum, 0, 4, stream);
    pool_q_norm<<<512, 256, 0, stream>>>(q, qn);
    pool_s_norm<<<1024, 256, 0, stream>>>(S, sn);
    sim_topk<<<1024, 256, 0, stream>>>(qn, sn, partial);
    topk_loss<<<NQ / 4, 256, 0, stream>>>(partial, accum);
    finalize_out<<<1, 1, 0, stream>>>(accum, (float*)d_out);
}

// Round 17
// 293.828 us; speedup vs baseline: 1.0625x; 1.0625x over previous
//
#include <hip/hip_runtime.h>
#include <hip/hip_bf16.h>
#include <stdint.h>

// Problem geometry (fixed by reference)
#define NQ 4096      // 64*8*8 query rows
#define NS 40960     // 32768 (s1) + 8192 (s_src)
#define CDIM 512
#define QT 256       // q rows per block: 4 waves x 64 q (2 groups of 32)
#define SC 32        // s rows per chunk (register-blocking unit only — no LDS)
#define NSPLIT 32    // s-dimension splits
#define SPER (NS / NSPLIT)   // 1280
#define NCHUNK (SPER / SC)   // 40
#define NCAND 960    // per-row candidates: 32 splits * 2 lane-halves * 15

typedef float f32x16 __attribute__((ext_vector_type(16)));
typedef unsigned int u32x4 __attribute__((ext_vector_type(4)));
typedef int i32x4 __attribute__((ext_vector_type(4)));
typedef int i32x8 __attribute__((ext_vector_type(8)));

__device__ __forceinline__ float bf2f(unsigned short u) {
    uint32_t x = ((uint32_t)u) << 16;
    return __builtin_bit_cast(float, x);
}

// fp4 e2m1 encode of y (already pre-scaled by 16; e8m0 operand scale 2^-4 undoes it).
__device__ __forceinline__ unsigned fp4enc(float y) {
    float m = fabsf(y);
    unsigned c = (m < 0.25f) ? 0u : (m < 0.75f) ? 1u : (m < 1.25f) ? 2u
               : (m < 1.75f) ? 3u : (m < 2.5f)  ? 4u : (m < 3.5f)  ? 5u
               : (m < 5.0f)  ? 6u : 7u;
    return c | ((__builtin_bit_cast(unsigned, y) >> 28) & 8u);
}

// Branchless sorted-desc insert: r[i] = med3(v, r[i-1], r[i]) for i=14..1, then max.
__device__ __forceinline__ void ins15(float (&r)[15], float v) {
#pragma unroll
    for (int i = 14; i >= 1; --i) r[i] = __builtin_amdgcn_fmed3f(v, r[i - 1], r[i]);
    r[0] = fmaxf(r[0], v);
}

// fp4 only reads regs [0:3] of the 8-reg MFMA operand (proven: R15 zero-filled
// [4:7] and passed exactly) — use undef high half to avoid zero-mov churn.
__device__ __forceinline__ i32x8 frag8(u32x4 v) {
    return __builtin_shufflevector(__builtin_bit_cast(i32x4, v),
                                   __builtin_bit_cast(i32x4, v),
                                   0, 1, 2, 3, -1, -1, -1, -1);
}

// ---------------- Phase A1: pool q (4x4 mean) + row-normalize -> fp4 ----------------
__global__ __launch_bounds__(256) void pool_q_norm(const float* __restrict__ q,
                                                   unsigned char* __restrict__ qn) {
    int bb = blockIdx.x >> 3, h = blockIdx.x & 7;
    int t = threadIdx.x, lane = t & 63, wid = t >> 6;
    float vals[2][8];
    float ss[8] = {0, 0, 0, 0, 0, 0, 0, 0};
#pragma unroll
    for (int e = 0; e < 2; ++e) {
        int c = 2 * t + e;
        const float* base = q + ((size_t)(bb * 512 + c) * 1024 + 4 * h * 32);
#pragma unroll
        for (int w2 = 0; w2 < 8; ++w2) vals[e][w2] = 0.f;
#pragma unroll
        for (int i = 0; i < 4; ++i) {
            const float4* row = (const float4*)(base + i * 32);
#pragma unroll
            for (int w2 = 0; w2 < 8; ++w2) {
                float4 v = row[w2];
                vals[e][w2] += (v.x + v.y) + (v.z + v.w);
            }
        }
#pragma unroll
        for (int w2 = 0; w2 < 8; ++w2) {
            vals[e][w2] *= (1.f / 16.f);
            ss[w2] += vals[e][w2] * vals[e][w2];
        }
    }
    __shared__ float red[8][4];
#pragma unroll
    for (int k = 0; k < 8; ++k) {
        float v = ss[k];
#pragma unroll
        for (int o = 32; o > 0; o >>= 1) v += __shfl_xor(v, o, 64);
        if (lane == 0) red[k][wid] = v;
    }
    __syncthreads();
#pragma unroll
    for (int w2 = 0; w2 < 8; ++w2) {
        float inv16 = rsqrtf(red[w2][0] + red[w2][1] + red[w2][2] + red[w2][3]) * 16.f;
        unsigned e0 = fp4enc(vals[0][w2] * inv16);
        unsigned e1 = fp4enc(vals[1][w2] * inv16);
        qn[(size_t)(bb * 64 + h * 8 + w2) * 256 + t] = (unsigned char)(e0 | (e1 << 4));
    }
}

// ------- Phase A2: pool S at BOTH scales + row-normalize -> fp4 (tile-free) -------
// R17 rewrite: no 40KB bf16 LDS tile, no bf16 roundtrips, no extra read pass.
// Thread t owns channels 2t,2t+1 for ALL 40 output rows (80 f32 in registers);
// rowsums via 40 shuffle-reduces + one tiny cross-wave LDS step; direct f32->fp4
// encode; byte t of each 256B row stored coalesced (64 consecutive bytes/wave).
__global__ __launch_bounds__(256, 2) void pool_s_norm(const float* __restrict__ S,
                                                      unsigned char* __restrict__ sn) {
    int bb = blockIdx.x >> 3, h2 = blockIdx.x & 7;
    int t = threadIdx.x, lane = t & 63, wid = t >> 6;
    float v[2][40];   // [channel e][row r]: r<32 = s1 (j*16+w1), r>=32 = src (w2)
#pragma unroll
    for (int e = 0; e < 2; ++e) {
        int c = 2 * t + e;
        const float* base = S + ((size_t)(bb * 512 + c) * 1024 + 4 * h2 * 32);
#pragma unroll
        for (int j = 0; j < 2; ++j) {
            const float4* r0 = (const float4*)(base + (2 * j) * 32);
            const float4* r1 = (const float4*)(base + (2 * j + 1) * 32);
#pragma unroll
            for (int f = 0; f < 8; ++f) {
                float4 a = r0[f], b2 = r1[f];
                v[e][j * 16 + 2 * f]     = (a.x + a.y + b2.x + b2.y) * 0.25f;
                v[e][j * 16 + 2 * f + 1] = (a.z + a.w + b2.z + b2.w) * 0.25f;
            }
        }
#pragma unroll
        for (int w2 = 0; w2 < 8; ++w2)
            v[e][32 + w2] = (v[e][2 * w2] + v[e][2 * w2 + 1] +
                             v[e][16 + 2 * w2] + v[e][16 + 2 * w2 + 1]) * 0.25f;
    }
    __shared__ float red[40][4];
    __shared__ float inv16s[40];
#pragma unroll
    for (int r = 0; r < 40; ++r) {
        float p = v[0][r] * v[0][r] + v[1][r] * v[1][r];
#pragma unroll
        for (int o = 32; o > 0; o >>= 1) p += __shfl_xor(p, o, 64);
        if (lane == 0) red[r][wid] = p;
    }
    __syncthreads();
    if (t < 40) inv16s[t] = rsqrtf(red[t][0] + red[t][1] + red[t][2] + red[t][3]) * 16.f;
    __syncthreads();
#pragma unroll
    for (int r = 0; r < 40; ++r) {
        float iv = inv16s[r];   // broadcast read
        unsigned e0 = fp4enc(v[0][r] * iv);
        unsigned e1 = fp4enc(v[1][r] * iv);
        int grow = (r < 32) ? (bb * 256 + (2 * h2 + (r >> 4)) * 16 + (r & 15))
                            : (32768 + bb * 64 + h2 * 8 + (r - 32));
        sn[(size_t)grow * 256 + t] = (unsigned char)(e0 | (e1 << 4));
    }
}

// ---------------- Phase B: MX-fp4 32x32x64 MFMA, barrier-free, 64q/wave ----------------
// R16 post-mortem: barrier-free direct-global is CORRECT and MFMA/FETCH behave, but
// the (256,4) 128-reg cap forced b-remat + no load hoisting (VGPR=52, latency-bound).
// R17: launch_bounds(256,2) -> 256-reg cap. 64 q/wave: b[2][8]=64 VGPR pinned
// resident; per-chunk a4[8] batch-load (8 independent global loads issued before the
// MFMA chain -> vmcnt-batched under the scan). No LDS/barriers: waves free-run,
// 2 independent waves/SIMD. L1/L2-resident A (8KB chunk, XCD-pinned 320KB split).
// Scan-in-MFMA-shadow ping-pong (cA/pB static names) from R13.
// 512 blocks x 256 threads: xcd=id&7, j=id>>3, y=xcd*4+(j&3), x=j>>2 (0..15).
__global__ __launch_bounds__(256, 2) void sim_topk(const unsigned char* __restrict__ qn,
                                                   const unsigned char* __restrict__ sn,
                                                   float* __restrict__ partial) {
    int id = blockIdx.x;
    int xcd = id & 7, j = id >> 3;     // j = 0..63
    int y = xcd * 4 + (j & 3);         // s-split 0..31, pinned to XCD
    int x = j >> 2;                    // q-tile 0..15
    int tid = threadIdx.x, lane = tid & 63, wid = tid >> 6;
    int rlo = lane & 31, hi = lane >> 5;
    int qbase = x * QT + wid * 64;
    int sbase = y * SPER;

    // B fragments (q side, fp4): 2 groups x 32 q rows; frag = 16B covering
    // channels [kk*64 + hi*32, +32).
    u32x4 b[2][8];
#pragma unroll
    for (int g = 0; g < 2; ++g) {
        const unsigned char* qp = qn + (size_t)(qbase + g * 32 + rlo) * 256 + hi * 16;
#pragma unroll
        for (int kk = 0; kk < 8; ++kk) b[g][kk] = *(const u32x4*)(qp + kk * 32);
    }

    float r0[15], r1[15];
#pragma unroll
    for (int i = 0; i < 15; ++i) { r0[i] = -2.0f; r1[i] = -2.0f; }

    f32x16 cA0, cA1, pB0, pB1;         // current / previous chunk accs (ping-pong)
#pragma unroll
    for (int e = 0; e < 16; ++e) { pB0[e] = -2.0f; pB1[e] = -2.0f; }

    // Lane's A-row base: row (sbase + rlo), byte offset hi*16 within each 32B k-group.
    const unsigned char* sp = sn + (size_t)(sbase + rlo) * 256 + hi * 16;

    for (int it = 0; it < NCHUNK / 2; ++it) {
        // ---- even chunk 2it -> cA; scan pB (chunk 2it-1) in the MFMA shadow ----
#pragma unroll
        for (int g = 0; g < 2; ++g)
#pragma unroll
            for (int kk = 0; kk < 8; ++kk) asm volatile("" : "+v"(b[g][kk]));
        const unsigned char* s0 = sp + (size_t)(2 * it) * SC * 256;
        u32x4 a4[8];
#pragma unroll
        for (int kk = 0; kk < 8; ++kk) a4[kk] = *(const u32x4*)(s0 + kk * 32);
#pragma unroll
        for (int e = 0; e < 16; ++e) { cA0[e] = 0.f; cA1[e] = 0.f; }
#pragma unroll
        for (int kk = 0; kk < 8; ++kk) {
            i32x8 a = frag8(a4[kk]);
            cA0 = __builtin_amdgcn_mfma_scale_f32_32x32x64_f8f6f4(
                a, frag8(b[0][kk]), cA0, 4, 4, 0, 0x7B7B7B7B, 0, 0x7B7B7B7B);
            cA1 = __builtin_amdgcn_mfma_scale_f32_32x32x64_f8f6f4(
                a, frag8(b[1][kk]), cA1, 4, 4, 0, 0x7B7B7B7B, 0, 0x7B7B7B7B);
            ins15(r0, pB0[2 * kk]);
            ins15(r0, pB0[2 * kk + 1]);
            ins15(r1, pB1[2 * kk]);
            ins15(r1, pB1[2 * kk + 1]);
        }
        // ---- odd chunk 2it+1 -> pB; scan cA (chunk 2it) ----
        const unsigned char* s1 = s0 + SC * 256;
        u32x4 a5[8];
#pragma unroll
        for (int kk = 0; kk < 8; ++kk) a5[kk] = *(const u32x4*)(s1 + kk * 32);
#pragma unroll
        for (int e = 0; e < 16; ++e) { pB0[e] = 0.f; pB1[e] = 0.f; }
#pragma unroll
        for (int kk = 0; kk < 8; ++kk) {
            i32x8 a = frag8(a5[kk]);
            pB0 = __builtin_amdgcn_mfma_scale_f32_32x32x64_f8f6f4(
                a, frag8(b[0][kk]), pB0, 4, 4, 0, 0x7B7B7B7B, 0, 0x7B7B7B7B);
            pB1 = __builtin_amdgcn_mfma_scale_f32_32x32x64_f8f6f4(
                a, frag8(b[1][kk]), pB1, 4, 4, 0, 0x7B7B7B7B, 0, 0x7B7B7B7B);
            ins15(r0, cA0[2 * kk]);
            ins15(r0, cA0[2 * kk + 1]);
            ins15(r1, cA1[2 * kk]);
            ins15(r1, cA1[2 * kk + 1]);
        }
    }
    // epilogue: scan the final chunk (NCHUNK-1)
#pragma unroll
    for (int e = 0; e < 16; ++e) { ins15(r0, pB0[e]); ins15(r1, pB1[e]); }

    // Emit: partial[qrow][split][sub][15], sub = hi
    int q0 = qbase + rlo;
    float* dst0 = partial + (((size_t)q0 * NSPLIT + y) * 2 + hi) * 15;
    float* dst1 = partial + (((size_t)(q0 + 32) * NSPLIT + y) * 2 + hi) * 15;
#pragma unroll
    for (int i = 0; i < 15; ++i) { dst0[i] = r0[i]; dst1[i] = r1[i]; }
}

// ---------------- Final: merge 960 candidates/row -> top15 -> LSE/top4 loss ----------------
// Wave per row, 4 rows/block, no per-round barriers, one atomicAdd per block.
__global__ __launch_bounds__(256) void topk_loss(const float* __restrict__ partial,
                                                 float* __restrict__ accum) {
    int t = threadIdx.x, lane = t & 63, wid = t >> 6;
    int r = blockIdx.x * 4 + wid;
    const float* src = partial + (size_t)r * NCAND;
    float v[15];
#pragma unroll
    for (int i = 0; i < 15; ++i) v[i] = src[lane + 64 * i];
    float m0 = 0.f, sexp = 0.f, top4 = 0.f;
#pragma unroll
    for (int round = 0; round < 15; ++round) {
        float m = v[0];
        int mi = lane * 16;
#pragma unroll
        for (int i = 1; i < 15; ++i)
            if (v[i] > m) { m = v[i]; mi = lane * 16 + i; }
#pragma unroll
        for (int o = 32; o > 0; o >>= 1) {
            float om = __shfl_xor(m, o, 64);
            int oi = __shfl_xor(mi, o, 64);
            if (om > m || (om == m && oi < mi)) { m = om; mi = oi; }
        }
        int wl = mi >> 4, wi = mi & 15;
#pragma unroll
        for (int i = 0; i < 15; ++i)
            if (i == wi && wl == lane) v[i] = -1e30f;   // static-index clear
        if (round == 0) m0 = m;
        sexp += expf(m - m0);
        if (round < 4) top4 += m;
    }
    float loss = m0 + logf(sexp) - 0.25f * top4;
    __shared__ float red[4];
    if (lane == 0) red[wid] = loss;
    __syncthreads();
    if (t == 0) atomicAdd(accum, red[0] + red[1] + red[2] + red[3]);
}

__global__ void finalize_out(const float* __restrict__ accum, float* __restrict__ out) {
    out[0] = accum[0] * (1.0f / (float)NQ);
}

// ---------------- Launch ----------------
extern "C" void kernel_launch(void* const* d_in, const int* in_sizes, int n_in,
                              void* d_out, int out_size, void* d_ws, size_t ws_size,
                              hipStream_t stream) {
    (void)in_sizes; (void)n_in; (void)out_size; (void)ws_size;
    const float* q = (const float*)d_in[0];
    const float* S = (const float*)d_in[1];
    char* ws = (char*)d_ws;
    unsigned char* qn = (unsigned char*)ws;                          //  1,048,576 B
    unsigned char* sn = (unsigned char*)(ws + 1048576);              // 10,485,760 B
    float* partial = (float*)(ws + 1048576 + 10485760);              // 15,728,640 B
    float* accum   = (float*)(ws + 1048576 + 10485760 + 15728640);   // 4 B

    hipMemsetAsync(accum, 0, 4, stream);
    pool_q_norm<<<512, 256, 0, stream>>>(q, qn);
    pool_s_norm<<<1024, 256, 0, stream>>>(S, sn);
    sim_topk<<<512, 256, 0, stream>>>(qn, sn, partial);
    topk_loss<<<NQ / 4, 256, 0, stream>>>(partial, accum);
    finalize_out<<<1, 1, 0, stream>>>(accum, (float*)d_out);
}

// Round 18
// 263.851 us; speedup vs baseline: 1.1833x; 1.1136x over previous
//
#include <hip/hip_runtime.h>
#include <hip/hip_bf16.h>
#include <stdint.h>

// Problem geometry (fixed by reference)
#define NQ 4096      // 64*8*8 query rows
#define NS 40960     // 32768 (s1) + 8192 (s_src)
#define CDIM 512
#define QT 256       // q rows per block: 4 waves x 64 q (2 groups of 32)
#define SC 32        // s rows per compute sub-chunk
#define NPAIR 20     // chunk-pairs per split (2 sub-chunks each)
#define NSPLIT 32    // s-dimension splits
#define SPER (NS / NSPLIT)   // 1280
#define NCAND 960    // per-row candidates: 32 splits * 2 lane-halves * 15

typedef float f32x16 __attribute__((ext_vector_type(16)));
typedef unsigned int u32x4 __attribute__((ext_vector_type(4)));
typedef int i32x4 __attribute__((ext_vector_type(4)));
typedef int i32x8 __attribute__((ext_vector_type(8)));

__device__ __forceinline__ unsigned short f2bf(float f) {
    uint32_t u = __builtin_bit_cast(uint32_t, f);
    u += 0x7fffu + ((u >> 16) & 1u);   // RNE (finite values only here)
    return (unsigned short)(u >> 16);
}
__device__ __forceinline__ float bf2f(unsigned short u) {
    uint32_t x = ((uint32_t)u) << 16;
    return __builtin_bit_cast(float, x);
}

// fp4 e2m1 encode of y (already pre-scaled by 16; e8m0 operand scale 2^-4 undoes it).
__device__ __forceinline__ unsigned fp4enc(float y) {
    float m = fabsf(y);
    unsigned c = (m < 0.25f) ? 0u : (m < 0.75f) ? 1u : (m < 1.25f) ? 2u
               : (m < 1.75f) ? 3u : (m < 2.5f)  ? 4u : (m < 3.5f)  ? 5u
               : (m < 5.0f)  ? 6u : 7u;
    return c | ((__builtin_bit_cast(unsigned, y) >> 28) & 8u);
}

// CK-proven cast pattern: generic -> AS1/AS3 via uintptr
__device__ __forceinline__ void async_load16(const void* g, void* l) {
    auto gp = reinterpret_cast<const __attribute__((address_space(1))) uint32_t*>(
        reinterpret_cast<uintptr_t>(g));
    auto lp = reinterpret_cast<__attribute__((address_space(3))) uint32_t*>(
        reinterpret_cast<uintptr_t>(l));
    __builtin_amdgcn_global_load_lds(gp, lp, 16 /*bytes, literal*/, 0, 0);
}

// Branchless sorted-desc insert: r[i] = med3(v, r[i-1], r[i]) for i=14..1, then max.
__device__ __forceinline__ void ins15(float (&r)[15], float v) {
#pragma unroll
    for (int i = 14; i >= 1; --i) r[i] = __builtin_amdgcn_fmed3f(v, r[i - 1], r[i]);
    r[0] = fmaxf(r[0], v);
}

// fp4 only reads regs [0:3] of the 8-reg MFMA operand (proven: R15 zero-filled
// [4:7] and passed exactly) — undef high half avoids zero-mov churn.
__device__ __forceinline__ i32x8 frag8(u32x4 v) {
    return __builtin_shufflevector(__builtin_bit_cast(i32x4, v),
                                   __builtin_bit_cast(i32x4, v),
                                   0, 1, 2, 3, -1, -1, -1, -1);
}

// ---------------- Phase A1: pool q (4x4 mean) + row-normalize -> fp4 ----------------
__global__ __launch_bounds__(256) void pool_q_norm(const float* __restrict__ q,
                                                   unsigned char* __restrict__ qn) {
    int bb = blockIdx.x >> 3, h = blockIdx.x & 7;
    int t = threadIdx.x, lane = t & 63, wid = t >> 6;
    float vals[2][8];
    float ss[8] = {0, 0, 0, 0, 0, 0, 0, 0};
#pragma unroll
    for (int e = 0; e < 2; ++e) {
        int c = 2 * t + e;
        const float* base = q + ((size_t)(bb * 512 + c) * 1024 + 4 * h * 32);
#pragma unroll
        for (int w2 = 0; w2 < 8; ++w2) vals[e][w2] = 0.f;
#pragma unroll
        for (int i = 0; i < 4; ++i) {
            const float4* row = (const float4*)(base + i * 32);
#pragma unroll
            for (int w2 = 0; w2 < 8; ++w2) {
                float4 v = row[w2];
                vals[e][w2] += (v.x + v.y) + (v.z + v.w);
            }
        }
#pragma unroll
        for (int w2 = 0; w2 < 8; ++w2) {
            vals[e][w2] *= (1.f / 16.f);
            ss[w2] += vals[e][w2] * vals[e][w2];
        }
    }
    __shared__ float red[8][4];
#pragma unroll
    for (int k = 0; k < 8; ++k) {
        float v = ss[k];
#pragma unroll
        for (int o = 32; o > 0; o >>= 1) v += __shfl_xor(v, o, 64);
        if (lane == 0) red[k][wid] = v;
    }
    __syncthreads();
#pragma unroll
    for (int w2 = 0; w2 < 8; ++w2) {
        float inv16 = rsqrtf(red[w2][0] + red[w2][1] + red[w2][2] + red[w2][3]) * 16.f;
        unsigned e0 = fp4enc(vals[0][w2] * inv16);
        unsigned e1 = fp4enc(vals[1][w2] * inv16);
        qn[(size_t)(bb * 64 + h * 8 + w2) * 256 + t] = (unsigned char)(e0 | (e1 << 4));
    }
}

// ------- Phase A2: pool S at BOTH scales + row-normalize -> fp4 (R15 version) -------
__global__ __launch_bounds__(256) void pool_s_norm(const float* __restrict__ S,
                                                   unsigned char* __restrict__ sn) {
    int bb = blockIdx.x >> 3, h2 = blockIdx.x & 7;
    int t = threadIdx.x, lane = t & 63, wid = t >> 6;
    __shared__ unsigned short tile[40 * 512];   // 40KB raw-bf16 values
    __shared__ float rowsum[40];
#pragma unroll
    for (int e = 0; e < 2; ++e) {
        int c = 2 * t + e;
        const float* base = S + ((size_t)(bb * 512 + c) * 1024 + 4 * h2 * 32);
        float s1v[2][16];
#pragma unroll
        for (int j = 0; j < 2; ++j) {
            const float4* r0 = (const float4*)(base + (2 * j) * 32);
            const float4* r1 = (const float4*)(base + (2 * j + 1) * 32);
#pragma unroll
            for (int f = 0; f < 8; ++f) {
                float4 a = r0[f], b2 = r1[f];
                s1v[j][2 * f]     = (a.x + a.y + b2.x + b2.y) * 0.25f;
                s1v[j][2 * f + 1] = (a.z + a.w + b2.z + b2.w) * 0.25f;
            }
        }
#pragma unroll
        for (int j = 0; j < 2; ++j)
#pragma unroll
            for (int w1 = 0; w1 < 16; ++w1)
                tile[(j * 16 + w1) * 512 + c] = f2bf(s1v[j][w1]);
#pragma unroll
        for (int w2 = 0; w2 < 8; ++w2) {
            float src = (s1v[0][2 * w2] + s1v[0][2 * w2 + 1] +
                         s1v[1][2 * w2] + s1v[1][2 * w2 + 1]) * 0.25f;
            tile[(32 + w2) * 512 + c] = f2bf(src);
        }
    }
    __syncthreads();
    // Row sums-of-squares: wave wid owns rows 4k+wid; 64 lanes x 8 bf16 per row.
#pragma unroll
    for (int k = 0; k < 10; ++k) {
        int row = 4 * k + wid;
        u32x4 d = *(const u32x4*)(&tile[row * 512 + lane * 8]);
        float s = 0.f;
#pragma unroll
        for (int j = 0; j < 4; ++j) {
            float x0 = bf2f((unsigned short)(d[j] & 0xffffu));
            float x1 = bf2f((unsigned short)(d[j] >> 16));
            s += x0 * x0 + x1 * x1;
        }
#pragma unroll
        for (int o = 32; o > 0; o >>= 1) s += __shfl_xor(s, o, 64);
        if (lane == 0) rowsum[row] = s;
    }
    __syncthreads();
    // Scale + fp4 cast + coalesced 4B stores: 40 rows x 64 4B-units.
#pragma unroll
    for (int k = 0; k < 10; ++k) {
        int idx = t + 256 * k;
        int r = idx >> 6, seg = idx & 63;      // seg of 8 channels -> 4 bytes
        float inv16 = rsqrtf(rowsum[r]) * 16.f;
        const unsigned short* src = &tile[r * 512 + seg * 8];
        unsigned out = 0;
#pragma unroll
        for (int m = 0; m < 8; ++m)
            out |= fp4enc(bf2f(src[m]) * inv16) << (4 * m);
        int grow = (r < 32) ? (bb * 256 + (2 * h2 + (r >> 4)) * 16 + (r & 15))
                            : (32768 + bb * 64 + h2 * 8 + (r - 32));
        *(unsigned*)(sn + (size_t)grow * 256 + seg * 4) = out;
    }
}

// ---------------- Phase B: MX-fp4 32x32x64 MFMA, chunk-PAIR staging ----------------
// R15 base (264us best) with ONE change: one vmcnt+barrier now covers a 64-row
// chunk-pair (two 32-row compute phases) -> 20 sync events instead of 40.
// Pair buffer = 16KB, triple-buffered (48KB/block, 2 blocks/CU = 96KB).
// Everything else identical to R15: fp4, 64q/wave (b[2][8]=64 VGPR pinned),
// cA/pB scan-in-MFMA-shadow ping-pong, slot^row swizzle, XCD-pinned splits.
// 512 blocks x 256 threads: xcd=id&7, j=id>>3, y=xcd*4+(j&3), x=j>>2 (0..15).
__global__ __launch_bounds__(256, 2) void sim_topk(const unsigned char* __restrict__ qn,
                                                   const unsigned char* __restrict__ sn,
                                                   float* __restrict__ partial) {
    __shared__ char Bs[3][2 * SC * 256];   // 3 x 16KB pair-buffers
    int id = blockIdx.x;
    int xcd = id & 7, j = id >> 3;     // j = 0..63
    int y = xcd * 4 + (j & 3);         // s-split 0..31, pinned to XCD
    int x = j >> 2;                    // q-tile 0..15
    int tid = threadIdx.x, lane = tid & 63, wid = tid >> 6;
    int rlo = lane & 31, hi = lane >> 5;
    int qbase = x * QT + wid * 64;
    int sbase = y * SPER;
    char* BsB = &Bs[0][0];

    // B fragments (q side, fp4): 2 groups x 32 q rows; frag = 16B covering
    // channels [kk*64 + hi*32, +32).
    u32x4 b[2][8];
#pragma unroll
    for (int g = 0; g < 2; ++g) {
        const unsigned char* qp = qn + (size_t)(qbase + g * 32 + rlo) * 256 + hi * 16;
#pragma unroll
        for (int kk = 0; kk < 8; ++kk) b[g][kk] = *(const u32x4*)(qp + kk * 32);
    }

    float r0[15], r1[15];
#pragma unroll
    for (int i = 0; i < 15; ++i) { r0[i] = -2.0f; r1[i] = -2.0f; }

    // Stage one 16KB chunk-pair (64 s-rows): 16 wave-instrs (4/wave).
    // Slot g = 0..1023: row = g>>4 (0..63), slot-in-row s = g&15, src pre-swizzled.
    auto stage = [&](int pr, int buf) {
#pragma unroll
        for (int ii = 0; ii < 4; ++ii) {
            int g = (wid * 4 + ii) * 64 + lane;
            int row = g >> 4, s = g & 15;
            size_t srcoff = (size_t)(sbase + pr * 2 * SC + row) * 256
                          + (size_t)((s ^ (row & 15)) << 4);
            async_load16(sn + srcoff, BsB + buf * 16384 + (g << 4));
        }
    };

    // One K=64 kstep for both q-groups: 1 swizzled b128 A-read -> 2 scaled MFMAs.
    auto kstep = [&](const char* B0, int kk, f32x16& acc0, f32x16& acc1) {
        int s0 = kk * 2 + hi;
        u32x4 a4 = *(const u32x4*)(B0 + rlo * 256 + ((s0 ^ (rlo & 15)) << 4));
        i32x8 a = frag8(a4);
        acc0 = __builtin_amdgcn_mfma_scale_f32_32x32x64_f8f6f4(
            a, frag8(b[0][kk]), acc0, 4, 4, 0, 0x7B7B7B7B, 0, 0x7B7B7B7B);
        acc1 = __builtin_amdgcn_mfma_scale_f32_32x32x64_f8f6f4(
            a, frag8(b[1][kk]), acc1, 4, 4, 0, 0x7B7B7B7B, 0, 0x7B7B7B7B);
    };

    stage(0, 0);
    stage(1, 1);
    f32x16 cA0, cA1, pB0, pB1;         // current / previous sub-chunk accs (ping-pong)
#pragma unroll
    for (int e = 0; e < 16; ++e) { pB0[e] = -2.0f; pB1[e] = -2.0f; }
    int bufR = 0, bufS = 2, prS = 2;

    for (int pr = 0; pr < NPAIR; ++pr) {
        // ONE sync event per 64-row pair (R15 paid this per 32-row phase).
        asm volatile("s_waitcnt vmcnt(8)" ::: "memory");   // pair pr landed (8 newer = pr+1)
        __builtin_amdgcn_s_barrier();
        stage(prS, bufS);
        prS = (prS + 1 == NPAIR) ? 0 : prS + 1;
        bufS = (bufS + 1 == 3) ? 0 : bufS + 1;
#pragma unroll
        for (int g = 0; g < 2; ++g)
#pragma unroll
            for (int kk = 0; kk < 8; ++kk) asm volatile("" : "+v"(b[g][kk]));
        const char* B0 = BsB + bufR * 16384;
        bufR = (bufR + 1 == 3) ? 0 : bufR + 1;

        // ---- sub-chunk 0 (rows 0..31) -> cA; scan pB (prev sub-chunk) ----
#pragma unroll
        for (int e = 0; e < 16; ++e) { cA0[e] = 0.f; cA1[e] = 0.f; }
#pragma unroll
        for (int kk = 0; kk < 8; ++kk) {
            kstep(B0, kk, cA0, cA1);
            ins15(r0, pB0[2 * kk]);
            ins15(r0, pB0[2 * kk + 1]);
            ins15(r1, pB1[2 * kk]);
            ins15(r1, pB1[2 * kk + 1]);
        }
        // ---- sub-chunk 1 (rows 32..63) -> pB; scan cA ----
        const char* B1 = B0 + 32 * 256;   // (32+rlo)&15 == rlo&15: same swizzle
#pragma unroll
        for (int e = 0; e < 16; ++e) { pB0[e] = 0.f; pB1[e] = 0.f; }
#pragma unroll
        for (int kk = 0; kk < 8; ++kk) {
            kstep(B1, kk, pB0, pB1);
            ins15(r0, cA0[2 * kk]);
            ins15(r0, cA0[2 * kk + 1]);
            ins15(r1, cA1[2 * kk]);
            ins15(r1, cA1[2 * kk + 1]);
        }
    }
    // epilogue: scan the final sub-chunk
#pragma unroll
    for (int e = 0; e < 16; ++e) { ins15(r0, pB0[e]); ins15(r1, pB1[e]); }

    // Emit: partial[qrow][split][sub][15], sub = hi
    int q0 = qbase + rlo;
    float* dst0 = partial + (((size_t)q0 * NSPLIT + y) * 2 + hi) * 15;
    float* dst1 = partial + (((size_t)(q0 + 32) * NSPLIT + y) * 2 + hi) * 15;
#pragma unroll
    for (int i = 0; i < 15; ++i) { dst0[i] = r0[i]; dst1[i] = r1[i]; }
}

// ---------------- Final: merge 960 candidates/row -> top15 -> LSE/top4 loss ----------------
// Wave per row, 4 rows/block, no per-round barriers, one atomicAdd per block.
__global__ __launch_bounds__(256) void topk_loss(const float* __restrict__ partial,
                                                 float* __restrict__ accum) {
    int t = threadIdx.x, lane = t & 63, wid = t >> 6;
    int r = blockIdx.x * 4 + wid;
    const float* src = partial + (size_t)r * NCAND;
    float v[15];
#pragma unroll
    for (int i = 0; i < 15; ++i) v[i] = src[lane + 64 * i];
    float m0 = 0.f, sexp = 0.f, top4 = 0.f;
#pragma unroll
    for (int round = 0; round < 15; ++round) {
        float m = v[0];
        int mi = lane * 16;
#pragma unroll
        for (int i = 1; i < 15; ++i)
            if (v[i] > m) { m = v[i]; mi = lane * 16 + i; }
#pragma unroll
        for (int o = 32; o > 0; o >>= 1) {
            float om = __shfl_xor(m, o, 64);
            int oi = __shfl_xor(mi, o, 64);
            if (om > m || (om == m && oi < mi)) { m = om; mi = oi; }
        }
        int wl = mi >> 4, wi = mi & 15;
#pragma unroll
        for (int i = 0; i < 15; ++i)
            if (i == wi && wl == lane) v[i] = -1e30f;   // static-index clear
        if (round == 0) m0 = m;
        sexp += expf(m - m0);
        if (round < 4) top4 += m;
    }
    float loss = m0 + logf(sexp) - 0.25f * top4;
    __shared__ float red[4];
    if (lane == 0) red[wid] = loss;
    __syncthreads();
    if (t == 0) atomicAdd(accum, red[0] + red[1] + red[2] + red[3]);
}

__global__ void finalize_out(const float* __restrict__ accum, float* __restrict__ out) {
    out[0] = accum[0] * (1.0f / (float)NQ);
}

// ---------------- Launch ----------------
extern "C" void kernel_launch(void* const* d_in, const int* in_sizes, int n_in,
                              void* d_out, int out_size, void* d_ws, size_t ws_size,
                              hipStream_t stream) {
    (void)in_sizes; (void)n_in; (void)out_size; (void)ws_size;
    const float* q = (const float*)d_in[0];
    const float* S = (const float*)d_in[1];
    char* ws = (char*)d_ws;
    unsigned char* qn = (unsigned char*)ws;                          //  1,048,576 B
    unsigned char* sn = (unsigned char*)(ws + 1048576);              // 10,485,760 B
    float* partial = (float*)(ws + 1048576 + 10485760);              // 15,728,640 B
    float* accum   = (float*)(ws + 1048576 + 10485760 + 15728640);   // 4 B

    hipMemsetAsync(accum, 0, 4, stream);
    pool_q_norm<<<512, 256, 0, stream>>>(q, qn);
    pool_s_norm<<<1024, 256, 0, stream>>>(S, sn);
    sim_topk<<<512, 256, 0, stream>>>(qn, sn, partial);
    topk_loss<<<NQ / 4, 256, 0, stream>>>(partial, accum);
    finalize_out<<<1, 1, 0, stream>>>(accum, (float*)d_out);
}